// Round 19
// baseline (436.319 us; speedup 1.0000x reference)
//
#include <hip/hip_runtime.h>
#include <math.h>

#define B_   32
#define L_   2048
#define DSEQ 1024
#define DGLB 1024
#define H_   16
#define DK_  64
#define DV_  64
#define LT   64
#define NT   (L_/LT)      // 32
#define PSTRIDE 66        // m, s, y[64]

// Wc4 layout (for 32x32x16 MFMA): [h][ks16(64)][cg(4)][kg(2)][col(32)][e(8)]
// d = ks16*16 + kg*8 + e ; j = cg*32 + col (j<64 -> Wk col, else Wv col-64)
// Wave chunk (h,ks16,cg): lane l reads 16B at l*16 -> col=l&31, kg=l>>5.
#define WC_K32STRIDE 4096          // u16 elems per k32 step (2 x 2048)
#define WC_HSTRIDE   131072        // u16 elems per head (4 MiB total)

#define AS1 __attribute__((address_space(1)))
#define AS3 __attribute__((address_space(3)))

using u16    = unsigned short;
using bf16x8 = __attribute__((ext_vector_type(8))) short;
using f32x4  = __attribute__((ext_vector_type(4))) float;
using f32x16 = __attribute__((ext_vector_type(16))) float;

__device__ __forceinline__ u16 f2bf(float x) {
  union { float f; unsigned int u; } v; v.f = x;
  return (u16)((v.u + 0x7fffu + ((v.u >> 16) & 1u)) >> 16);   // RNE
}

__device__ __forceinline__ float tanh_fast(float x) {
  float e = __builtin_exp2f(x * 2.885390081777927f);   // 2*log2(e)
  return 1.f - 2.f/(e + 1.f);
}

__device__ __forceinline__ float erf_fast(float x) {
  float ax = fabsf(x);
  float t  = 1.f/(1.f + 0.3275911f*ax);
  float p  = t*(0.254829592f + t*(-0.284496736f + t*(1.421413741f +
             t*(-1.453152027f + t*1.061405429f))));
  float e  = __builtin_exp2f(-ax*ax*1.4426950408889634f);  // e^{-x^2}
  float r  = 1.f - p*e;
  return copysignf(r, x);
}

#define PHASE_BARRIER(N)                                   \
  do {                                                     \
    __builtin_amdgcn_sched_barrier(0);                     \
    asm volatile("s_waitcnt vmcnt(" #N ")" ::: "memory");  \
    __builtin_amdgcn_s_barrier();                          \
    __builtin_amdgcn_sched_barrier(0);                     \
  } while (0)

// Wc4 pack; grid (H, 128 cols), 256 threads over d
__global__ void pack_w_kernel(const float* __restrict__ Wk,
                              const float* __restrict__ Wv,
                              u16* __restrict__ Wc) {
  const int h = blockIdx.x, j = blockIdx.y;
  const int cg = j >> 5, col = j & 31;
  const float* src = (j < DK_) ? (Wk + (size_t)h*DSEQ*DK_ + j)
                               : (Wv + (size_t)h*DSEQ*DV_ + (j - DK_));
  u16* dst = Wc + (size_t)h*WC_HSTRIDE + (size_t)cg*512 + (size_t)col*8;
  for (int d = threadIdx.x; d < DSEQ; d += blockDim.x) {
    int ks16 = d >> 4, kg = (d >> 3) & 1, e = d & 7;
    dst[(size_t)ks16*2048 + kg*256 + e] = f2bf(src[(size_t)d*64]);
  }
}

// S (fp32) -> Sb (bf16), flat; 8-elem granules, coalesced
__global__ void s2bf_kernel(const float* __restrict__ S, u16* __restrict__ Sb) {
  const size_t G = (size_t)B_*L_*DSEQ/8;
  for (size_t i = (size_t)blockIdx.x*256 + threadIdx.x; i < G; i += (size_t)4096*256) {
    const float4* sp = (const float4*)(S + i*8);
    float4 v0 = sp[0], v1 = sp[1];
    bf16x8 wv;
    wv[0]=(short)f2bf(v0.x); wv[1]=(short)f2bf(v0.y);
    wv[2]=(short)f2bf(v0.z); wv[3]=(short)f2bf(v0.w);
    wv[4]=(short)f2bf(v1.x); wv[5]=(short)f2bf(v1.y);
    wv[6]=(short)f2bf(v1.z); wv[7]=(short)f2bf(v1.w);
    *(bf16x8*)(Sb + i*8) = wv;
  }
}

// Q[b][h][k] = tanh(sum_d X[b,d]*Wq[h,d,k]); grid (H, B/4), 256 thr.
// Coalesced (r17): threads (dd=tid>>6, k=tid&63); LDS reduce over dd.
__global__ void q_proj_kernel(const float* __restrict__ X,
                              const float* __restrict__ Wq,
                              float* __restrict__ Q) {
  __shared__ float red[4][4][64];   // [dd][bb][k]
  const int h = blockIdx.x, b0 = blockIdx.y*4;
  const int k = threadIdx.x & 63, dd = threadIdx.x >> 6;
  const float* w = Wq + (size_t)h*DGLB*DK_ + (size_t)dd*256*DK_ + k;
  float a0=0.f, a1=0.f, a2=0.f, a3=0.f;
  for (int d = 0; d < 256; ++d) {
    float wv = w[(size_t)d*DK_];
    a0 += X[(size_t)(b0+0)*DGLB + dd*256 + d]*wv;
    a1 += X[(size_t)(b0+1)*DGLB + dd*256 + d]*wv;
    a2 += X[(size_t)(b0+2)*DGLB + dd*256 + d]*wv;
    a3 += X[(size_t)(b0+3)*DGLB + dd*256 + d]*wv;
  }
  red[dd][0][k]=a0; red[dd][1][k]=a1; red[dd][2][k]=a2; red[dd][3][k]=a3;
  __syncthreads();
  if (dd == 0) {
    #pragma unroll
    for (int bb = 0; bb < 4; ++bb) {
      float s = red[0][bb][k]+red[1][bb][k]+red[2][bb][k]+red[3][bb][k];
      Q[((size_t)(b0+bb)*H_+h)*DK_+k] = tanhf(s);
    }
  }
}

// grid: 8192 linear blocks, 256 threads = 4 waves, 3 blocks/CU.
// r18 pairing + pipeline, MFMA shape upgraded to 32x32x16 (2x FLOP/instr,
// +20% pipe ceiling, half the issue slots). Wave tile 64 rows x 64 cols =
// 2x2 of 32x32, acc2[2][2] f32x16 (64 regs, same as before).
// A/B lane maps (16x16 analogy): A row=lane&31, B col=lane&31, k-group of
// 8 = lane>>5. C/D (verified m74/m101): col=lane&31,
// row=(reg&3)+8*(reg>>2)+4*(lane>>5).
// A-side LDS layout/staging/swizzle IDENTICAL to r18 (rows 256 B, granule
// ^ (row&15), gload_lds source-swizzled). Per KSTEP: 4 ds_read + 8 MFMA
// (was 4 + 16). B from Wc4: 1 KB contiguous per (ks16, colgrp) chunk.
template<int BF16SRC>
__global__ __launch_bounds__(256, 3) void fused_kernel(
    const float* __restrict__ S, const u16* __restrict__ Sb,
    const u16* __restrict__ Wc, const float* __restrict__ Q,
    float* __restrict__ part) {
  __shared__ u16   Slds[3*64*128];   // 3 x 16 KB, rows 256 B
  __shared__ float lpart[2][64];

  const int id   = blockIdx.x;
  const int xcd  = id & 7;
  const int jg   = xcd >> 1;         // head-group 0..3 (pairs 2jg, 2jg+1)
  const int cpar = xcd & 1;          // tile parity
  const int idx  = id >> 3;          // 0..1023
  const int psel = idx & 1;
  const int mm   = idx >> 1;         // 0..511
  const int pair = 2*jg + psel;      // 0..7
  const int tile = (((mm + (jg << 7)) & 511) << 1) | cpar;   // 0..1023
  const int t    = tile & (NT-1), b = tile >> 5;

  const int tid  = threadIdx.x;
  const int wave = tid >> 6, lane = tid & 63;
  const int l31  = lane & 31, kg5 = lane >> 5, l15 = lane & 15;
  const int isV  = wave & 1,  hp  = wave >> 1;
  const int h    = pair*2 + hp;

  // B per-lane base: colgrp = isV*2 (+ct), col = l31, kgroup = kg5
  const u16* wb = Wc + (size_t)h*WC_HSTRIDE
                     + (size_t)(isV*2)*512 + (size_t)kg5*256 + (size_t)l31*8;
  int arow2[2];
  #pragma unroll
  for (int rt2 = 0; rt2 < 2; ++rt2) arow2[rt2] = (rt2*32 + l31)*256;  // bytes

  const u16*   Sv = Sb + ((size_t)b*L_ + (size_t)t*LT)*DSEQ;
  const float* Sf = S  + ((size_t)b*L_ + (size_t)t*LT)*DSEQ;

  // stage sub-tile (sub: 64 rows x 128 k = 16 KB) into buf[sub%3] — r18
  auto stage_gl = [&](int sub) {
    const int bs = (sub % 3) * 8192;           // u16 offset (16 KB)
    const int ko = (sub & 7) * 128;
    #pragma unroll
    for (int it = 0; it < 4; ++it) {
      const int jj  = wave*4 + it;
      const int row = 4*jj + (lane >> 4);
      const int g   = (lane & 15) ^ (row & 15);
      const u16* gp = Sv + (size_t)row*DSEQ + ko + (g << 3);
      __builtin_amdgcn_global_load_lds(
          (const AS1 void*)gp, (AS3 void*)(Slds + bs + jj*512), 16, 0, 0);
    }
  };
  auto stage_reg = [&](int sub) {              // fp32 fallback
    const int bs = (sub % 3) * 16384;          // bytes
    const int ko = (sub & 7) * 128;
    #pragma unroll
    for (int it = 0; it < 4; ++it) {
      int f = it*256 + tid, row = f >> 4, q = f & 15;
      int g = q ^ (row & 15);
      const float4* sp = (const float4*)(Sf + (size_t)row*DSEQ + ko + g*8);
      float4 v0 = sp[0], v1 = sp[1];
      bf16x8 wv;
      wv[0]=(short)f2bf(v0.x); wv[1]=(short)f2bf(v0.y);
      wv[2]=(short)f2bf(v0.z); wv[3]=(short)f2bf(v0.w);
      wv[4]=(short)f2bf(v1.x); wv[5]=(short)f2bf(v1.y);
      wv[6]=(short)f2bf(v1.z); wv[7]=(short)f2bf(v1.w);
      *(bf16x8*)((char*)Slds + bs + row*256 + q*16) = wv;
    }
  };

  f32x16 acc2[2][2];
  #pragma unroll
  for (int rt2 = 0; rt2 < 2; ++rt2)
    #pragma unroll
    for (int ct = 0; ct < 2; ++ct)
      #pragma unroll
      for (int e = 0; e < 16; ++e) acc2[rt2][ct][e] = 0.f;

  // prologue: stage subs 0,1 first, then B init (k32 steps 0..3)
  if (BF16SRC) {
    stage_gl(0);
    stage_gl(1);
    __builtin_amdgcn_sched_barrier(0);
  }
  // BUF[kh*2+ct]: kh = ks16 half of the k32 step, ct = col-tile
  bf16x8 bA[4], bB[4], bC[4], bD[4];
  #pragma unroll
  for (int c = 0; c < 4; ++c)
    bA[c] = *(const bf16x8*)(wb + (size_t)0*WC_K32STRIDE + (c>>1)*2048 + (c&1)*512);
  #pragma unroll
  for (int c = 0; c < 4; ++c)
    bB[c] = *(const bf16x8*)(wb + (size_t)1*WC_K32STRIDE + (c>>1)*2048 + (c&1)*512);
  #pragma unroll
  for (int c = 0; c < 4; ++c)
    bC[c] = *(const bf16x8*)(wb + (size_t)2*WC_K32STRIDE + (c>>1)*2048 + (c&1)*512);
  #pragma unroll
  for (int c = 0; c < 4; ++c)
    bD[c] = *(const bf16x8*)(wb + (size_t)3*WC_K32STRIDE + (c>>1)*2048 + (c&1)*512);
  const u16* wbp = wb + (size_t)4*WC_K32STRIDE;  // rolling refill pointer
  if (BF16SRC) PHASE_BARRIER(20);   // stage(0) done; stage(1)+Binit in flight

  // one k32 step: 4 ds_read + 8 MFMA(32x32x16); refill BUF with step +4
#define KSTEP(BUF, kk)                                                        \
  do {                                                                        \
    __builtin_amdgcn_s_setprio(1);                                            \
    _Pragma("unroll")                                                         \
    for (int kh = 0; kh < 2; ++kh) {                                          \
      _Pragma("unroll")                                                       \
      for (int rt2 = 0; rt2 < 2; ++rt2) {                                     \
        bf16x8 af = *(const bf16x8*)(cb + arow2[rt2] +                        \
                     (((((kk)*4 + kh*2 + kg5)) ^ l15) << 4));                 \
        acc2[rt2][0] = __builtin_amdgcn_mfma_f32_32x32x16_bf16(af, BUF[kh*2+0], acc2[rt2][0], 0,0,0); \
        acc2[rt2][1] = __builtin_amdgcn_mfma_f32_32x32x16_bf16(af, BUF[kh*2+1], acc2[rt2][1], 0,0,0); \
      }                                                                       \
    }                                                                         \
    __builtin_amdgcn_s_setprio(0);                                            \
    BUF[0] = *(const bf16x8*)(wbp);                                           \
    BUF[1] = *(const bf16x8*)(wbp + 512);                                     \
    BUF[2] = *(const bf16x8*)(wbp + 2048);                                    \
    BUF[3] = *(const bf16x8*)(wbp + 2560);                                    \
    wbp += ((s*4 + (kk) + 4) == 31) ? -(ptrdiff_t)(31*WC_K32STRIDE)           \
                                    : (ptrdiff_t)WC_K32STRIDE;                \
  } while (0)

  #pragma unroll
  for (int s = 0; s < 8; ++s) {
    if (BF16SRC) {
      if (s < 6) { stage_gl(s + 2); __builtin_amdgcn_sched_barrier(0); }
    } else {
      stage_reg(s);
      __syncthreads();
    }
    const char* cb = (const char*)Slds + (s % 3)*16384;
    KSTEP(bA, 0); KSTEP(bB, 1); KSTEP(bC, 2); KSTEP(bD, 3);
    if (BF16SRC) {
      // issued since stage(s+1): prev-phase B (16) + this phase (4+16) = 36
      if (s < 6)       PHASE_BARRIER(36);
      else if (s == 6) PHASE_BARRIER(32);
    } else {
      __syncthreads();
    }
  }
#undef KSTEP

  if (!isV) {
    // K-proj: tanh, dot with Q over 64 k-cols, reduce over 32-lane halves
    const float* Qb = Q + ((size_t)b*H_ + h)*DK_;
    float ql0 = Qb[l31];
    float ql1 = Qb[32 + l31];
    #pragma unroll
    for (int rt2 = 0; rt2 < 2; ++rt2) {
      #pragma unroll
      for (int rg = 0; rg < 16; ++rg) {
        float pl = ql0*tanh_fast(acc2[rt2][0][rg])
                 + ql1*tanh_fast(acc2[rt2][1][rg]);
        pl += __shfl_xor(pl, 1); pl += __shfl_xor(pl, 2);
        pl += __shfl_xor(pl, 4); pl += __shfl_xor(pl, 8);
        pl += __shfl_xor(pl, 16);
        if (l31 == 0)
          lpart[hp][rt2*32 + (rg&3) + 8*(rg>>2) + 4*kg5] = pl;
      }
    }
  } else {
    // V-proj: gelu in place
    #pragma unroll
    for (int rt2 = 0; rt2 < 2; ++rt2)
      #pragma unroll
      for (int ct = 0; ct < 2; ++ct)
        #pragma unroll
        for (int rg = 0; rg < 16; ++rg) {
          float x = acc2[rt2][ct][rg];
          acc2[rt2][ct][rg] = 0.5f*x*(1.f + erf_fast(x*0.70710678118654752f));
        }
  }
  __syncthreads();

  if (isV) {
    // softmax stats over this tile's 64 rows (lane <-> row)
    float lg = lpart[hp][lane] * 0.125f;   // 1/sqrt(64)
    float mx = lg;
    #pragma unroll
    for (int mk = 1; mk < 64; mk <<= 1) mx = fmaxf(mx, __shfl_xor(mx, mk));
    float ev = __expf(lg - mx);
    float sv = ev;
    #pragma unroll
    for (int mk = 1; mk < 64; mk <<= 1) sv += __shfl_xor(sv, mk);

    // weighted sum: per lane (col), rows live in regs; fetch e per rowmap
    float y0 = 0.f, y1 = 0.f;
    #pragma unroll
    for (int rt2 = 0; rt2 < 2; ++rt2)
      #pragma unroll
      for (int rg = 0; rg < 16; ++rg) {
        float e = __shfl(ev, rt2*32 + (rg&3) + 8*(rg>>2) + 4*kg5);
        y0 += e*acc2[rt2][0][rg];
        y1 += e*acc2[rt2][1][rg];
      }
    y0 += __shfl_xor(y0, 32);
    y1 += __shfl_xor(y1, 32);

    float* pt = part + (((size_t)b*H_ + h)*NT + t)*PSTRIDE;
    if (lane < 32) { pt[2 + lane] = y0; pt[2 + 32 + lane] = y1; }
    if (lane == 0) { pt[0] = mx; pt[1] = sv; }
  }
}

// merge NT tile-partials per (b,h); grid (H, B), block 64
__global__ void finalize_kernel(const float* __restrict__ part,
                                float* __restrict__ out) {
  const int h = blockIdx.x, b = blockIdx.y, v = threadIdx.x;
  const float* p = part + ((size_t)b*H_ + h)*(size_t)NT*PSTRIDE;
  float M = -3.0e38f;
  for (int tt = 0; tt < NT; ++tt) M = fmaxf(M, p[tt*PSTRIDE]);
  float ss = 0.f, y = 0.f;
  for (int tt = 0; tt < NT; ++tt) {
    float w = expf(p[tt*PSTRIDE] - M);
    ss += w*p[tt*PSTRIDE + 1];
    y  += w*p[tt*PSTRIDE + 2 + v];
  }
  out[((size_t)b*H_ + h)*DV_ + v] = y/ss;
}

extern "C" void kernel_launch(void* const* d_in, const int* in_sizes, int n_in,
                              void* d_out, int out_size, void* d_ws, size_t ws_size,
                              hipStream_t stream) {
  const float* X  = (const float*)d_in[0];
  const float* S  = (const float*)d_in[1];
  const float* Wq = (const float*)d_in[2];
  const float* Wk = (const float*)d_in[3];
  const float* Wv = (const float*)d_in[4];
  float* out = (float*)d_out;

  char* ws = (char*)d_ws;
  u16*   Wc    = (u16*)ws;                              // 4 MiB (Wc4 layout)
  float* Qbuf  = (float*)(ws + (4u<<20));               // 128 KiB
  float* part  = (float*)(ws + (4u<<20) + (128u<<10));  // ~4.3 MiB
  u16*   Sb    = (u16*)(ws + (16u<<20));                // 128 MiB (optional)
  const bool useBf = ws_size >= (144ull << 20);

  pack_w_kernel  <<<dim3(H_, 128),  256, 0, stream>>>(Wk, Wv, Wc);
  q_proj_kernel  <<<dim3(H_, B_/4), 256, 0, stream>>>(X, Wq, Qbuf);
  if (useBf) {
    s2bf_kernel       <<<dim3(4096), 256, 0, stream>>>(S, Sb);
    fused_kernel<1>   <<<dim3(8192), 256, 0, stream>>>(S, Sb, Wc, Qbuf, part);
  } else {
    fused_kernel<0>   <<<dim3(8192), 256, 0, stream>>>(S, Sb, Wc, Qbuf, part);
  }
  finalize_kernel<<<dim3(H_, B_),    64, 0, stream>>>(part, out);
}

// Round 20
// 416.853 us; speedup vs baseline: 1.0467x; 1.0467x over previous
//
#include <hip/hip_runtime.h>
#include <math.h>

#define B_   32
#define L_   2048
#define DSEQ 1024
#define DGLB 1024
#define H_   16
#define DK_  64
#define DV_  64
#define LT   64
#define NT   (L_/LT)      // 32
#define PSTRIDE 66        // m, s, y[64]

// Wc2 layout: [h][ks(32)][j(128)][e(32)] bf16; d = ks*32 + e
#define WC_KSTRIDE 4096            // 128*32 elems per k-step
#define WC_HSTRIDE 131072          // 32*4096 elems per head

#define AS1 __attribute__((address_space(1)))
#define AS3 __attribute__((address_space(3)))

using u16    = unsigned short;
using bf16x8 = __attribute__((ext_vector_type(8))) short;
using f32x4  = __attribute__((ext_vector_type(4))) float;

__device__ __forceinline__ u16 f2bf(float x) {
  union { float f; unsigned int u; } v; v.f = x;
  return (u16)((v.u + 0x7fffu + ((v.u >> 16) & 1u)) >> 16);   // RNE
}

__device__ __forceinline__ float tanh_fast(float x) {
  float e = __builtin_exp2f(x * 2.885390081777927f);   // 2*log2(e)
  return 1.f - 2.f/(e + 1.f);
}

__device__ __forceinline__ float erf_fast(float x) {
  float ax = fabsf(x);
  float t  = 1.f/(1.f + 0.3275911f*ax);
  float p  = t*(0.254829592f + t*(-0.284496736f + t*(1.421413741f +
             t*(-1.453152027f + t*1.061405429f))));
  float e  = __builtin_exp2f(-ax*ax*1.4426950408889634f);  // e^{-x^2}
  float r  = 1.f - p*e;
  return copysignf(r, x);
}

#define PHASE_BARRIER(N)                                   \
  do {                                                     \
    __builtin_amdgcn_sched_barrier(0);                     \
    asm volatile("s_waitcnt vmcnt(" #N ")" ::: "memory");  \
    __builtin_amdgcn_s_barrier();                          \
    __builtin_amdgcn_sched_barrier(0);                     \
  } while (0)

// Wc2[h][d>>5][j][d&31]: j<64 -> Wk[h,:,j], else Wv[h,:,j-64]
__global__ void pack_w_kernel(const float* __restrict__ Wk,
                              const float* __restrict__ Wv,
                              u16* __restrict__ Wc) {
  const int h = blockIdx.x, j = blockIdx.y;
  const float* src = (j < DK_) ? (Wk + (size_t)h*DSEQ*DK_ + j)
                               : (Wv + (size_t)h*DSEQ*DV_ + (j - DK_));
  u16* dst = Wc + (size_t)h*WC_HSTRIDE + (size_t)j*32;
  for (int d = threadIdx.x; d < DSEQ; d += blockDim.x)
    dst[(size_t)(d >> 5)*WC_KSTRIDE + (d & 31)] = f2bf(src[(size_t)d*64]);
}

// S (fp32) -> Sb (bf16), flat; 8-elem granules, coalesced
__global__ void s2bf_kernel(const float* __restrict__ S, u16* __restrict__ Sb) {
  const size_t G = (size_t)B_*L_*DSEQ/8;
  for (size_t i = (size_t)blockIdx.x*256 + threadIdx.x; i < G; i += (size_t)4096*256) {
    const float4* sp = (const float4*)(S + i*8);
    float4 v0 = sp[0], v1 = sp[1];
    bf16x8 wv;
    wv[0]=(short)f2bf(v0.x); wv[1]=(short)f2bf(v0.y);
    wv[2]=(short)f2bf(v0.z); wv[3]=(short)f2bf(v0.w);
    wv[4]=(short)f2bf(v1.x); wv[5]=(short)f2bf(v1.y);
    wv[6]=(short)f2bf(v1.z); wv[7]=(short)f2bf(v1.w);
    *(bf16x8*)(Sb + i*8) = wv;
  }
}

// Q[b][h][k] = tanh(sum_d X[b,d]*Wq[h,d,k]); grid (H, B/4), 256 thr.
// Coalesced (r17): threads (dd=tid>>6, k=tid&63); LDS reduce over dd.
__global__ void q_proj_kernel(const float* __restrict__ X,
                              const float* __restrict__ Wq,
                              float* __restrict__ Q) {
  __shared__ float red[4][4][64];   // [dd][bb][k]
  const int h = blockIdx.x, b0 = blockIdx.y*4;
  const int k = threadIdx.x & 63, dd = threadIdx.x >> 6;
  const float* w = Wq + (size_t)h*DGLB*DK_ + (size_t)dd*256*DK_ + k;
  float a0=0.f, a1=0.f, a2=0.f, a3=0.f;
  for (int d = 0; d < 256; ++d) {
    float wv = w[(size_t)d*DK_];
    a0 += X[(size_t)(b0+0)*DGLB + dd*256 + d]*wv;
    a1 += X[(size_t)(b0+1)*DGLB + dd*256 + d]*wv;
    a2 += X[(size_t)(b0+2)*DGLB + dd*256 + d]*wv;
    a3 += X[(size_t)(b0+3)*DGLB + dd*256 + d]*wv;
  }
  red[dd][0][k]=a0; red[dd][1][k]=a1; red[dd][2][k]=a2; red[dd][3][k]=a3;
  __syncthreads();
  if (dd == 0) {
    #pragma unroll
    for (int bb = 0; bb < 4; ++bb) {
      float s = red[0][bb][k]+red[1][bb][k]+red[2][bb][k]+red[3][bb][k];
      Q[((size_t)(b0+bb)*H_+h)*DK_+k] = tanhf(s);
    }
  }
}

// grid: 8192 linear blocks, 256 threads = 4 waves, 4 blocks/CU.
// r18 pairing (verified: FETCH 528->267 MB) + 2-BUFFER pipeline for the
// extra occupancy step: LDS 2 x 16 KB = 33 KB/block -> 4 blocks/CU
// (133 KB < 160), launch_bounds(256,4) -> 128-reg cap. To fit: B prefetch
// distance 2 (bA,bB only; live ~= acc 64 + B 32 + misc 25 ~= 120 < 128).
// Pipeline: phase s computes buf[s&1]; stage(s+1) issued at phase START
// (distance ~1 phase ~3K cyc > 900 cy HBM); end-of-phase counted
// vmcnt(16) (16 B-refills issued after the 4 stage loads; FIFO-sound).
// Wave = (hp, K|V), tile 64 rows x 64 cols, acc[4][4], 16x16x32 MFMA.
template<int BF16SRC>
__global__ __launch_bounds__(256, 4) void fused_kernel(
    const float* __restrict__ S, const u16* __restrict__ Sb,
    const u16* __restrict__ Wc, const float* __restrict__ Q,
    float* __restrict__ part) {
  __shared__ u16   Slds[2*64*128];   // 2 x 16 KB, rows 256 B
  __shared__ float lpart[2][64];

  const int id   = blockIdx.x;
  const int xcd  = id & 7;
  const int jg   = xcd >> 1;         // head-group 0..3 (pairs 2jg, 2jg+1)
  const int cpar = xcd & 1;          // tile parity
  const int idx  = id >> 3;          // 0..1023
  const int psel = idx & 1;
  const int mm   = idx >> 1;         // 0..511
  const int pair = 2*jg + psel;      // 0..7
  const int tile = (((mm + (jg << 7)) & 511) << 1) | cpar;   // 0..1023
  const int t    = tile & (NT-1), b = tile >> 5;

  const int tid  = threadIdx.x;
  const int wave = tid >> 6, lane = tid & 63;
  const int lhi  = lane >> 4, llo = lane & 15;
  const int isV  = wave & 1,  hp  = wave >> 1;
  const int h    = pair*2 + hp;

  const u16* wb = Wc + (size_t)h*WC_HSTRIDE + (size_t)(isV*64 + llo)*32 + lhi*8;
  int arow[4];
  #pragma unroll
  for (int rt = 0; rt < 4; ++rt) arow[rt] = (rt*16 + llo)*256;  // bytes

  const u16*   Sv = Sb + ((size_t)b*L_ + (size_t)t*LT)*DSEQ;
  const float* Sf = S  + ((size_t)b*L_ + (size_t)t*LT)*DSEQ;

  // stage sub-tile (sub: 64 rows x 128 k = 16 KB) into buf[sub&1]
  auto stage_gl = [&](int sub) {
    const int bs = (sub & 1) * 8192;           // u16 offset (16 KB)
    const int ko = (sub & 7) * 128;
    #pragma unroll
    for (int it = 0; it < 4; ++it) {
      const int jj  = wave*4 + it;
      const int row = 4*jj + (lane >> 4);
      const int g   = (lane & 15) ^ (row & 15);
      const u16* gp = Sv + (size_t)row*DSEQ + ko + (g << 3);
      __builtin_amdgcn_global_load_lds(
          (const AS1 void*)gp, (AS3 void*)(Slds + bs + jj*512), 16, 0, 0);
    }
  };
  auto stage_reg = [&](int sub) {              // fp32 fallback
    const int bs = (sub & 1) * 16384;          // bytes
    const int ko = (sub & 7) * 128;
    #pragma unroll
    for (int it = 0; it < 4; ++it) {
      int f = it*256 + tid, row = f >> 4, q = f & 15;
      int g = q ^ (row & 15);
      const float4* sp = (const float4*)(Sf + (size_t)row*DSEQ + ko + g*8);
      float4 v0 = sp[0], v1 = sp[1];
      bf16x8 wv;
      wv[0]=(short)f2bf(v0.x); wv[1]=(short)f2bf(v0.y);
      wv[2]=(short)f2bf(v0.z); wv[3]=(short)f2bf(v0.w);
      wv[4]=(short)f2bf(v1.x); wv[5]=(short)f2bf(v1.y);
      wv[6]=(short)f2bf(v1.z); wv[7]=(short)f2bf(v1.w);
      *(bf16x8*)((char*)Slds + bs + row*256 + q*16) = wv;
    }
  };

  f32x4 acc[4][4];
  #pragma unroll
  for (int rt = 0; rt < 4; ++rt)
    #pragma unroll
    for (int cc = 0; cc < 4; ++cc) acc[rt][cc] = {0.f,0.f,0.f,0.f};

  // prologue: stage sub 0 (pinned first), then B init (steps 0,1)
  if (BF16SRC) {
    stage_gl(0);
    __builtin_amdgcn_sched_barrier(0);
  }
  bf16x8 bA[4], bB[4];
  #pragma unroll
  for (int cc = 0; cc < 4; ++cc) bA[cc] = *(const bf16x8*)(wb + (size_t)0*WC_KSTRIDE + cc*512);
  #pragma unroll
  for (int cc = 0; cc < 4; ++cc) bB[cc] = *(const bf16x8*)(wb + (size_t)1*WC_KSTRIDE + cc*512);
  const u16* wbp = wb + (size_t)2*WC_KSTRIDE;  // rolling refill pointer
  if (BF16SRC) PHASE_BARRIER(8);               // stage(0) done; B-init in flight

  // one k-step (32 elems): consume BUF (step s*4+kk), refill with step +2
#define KSTEP(BUF, kk)                                                        \
  do {                                                                        \
    const int colb = (((kk)*4 + lhi) ^ llo) << 4;                             \
    __builtin_amdgcn_s_setprio(1);                                            \
    _Pragma("unroll")                                                         \
    for (int rt = 0; rt < 4; ++rt) {                                          \
      bf16x8 af = *(const bf16x8*)(cb + arow[rt] + colb);                     \
      acc[rt][0] = __builtin_amdgcn_mfma_f32_16x16x32_bf16(af, BUF[0], acc[rt][0], 0,0,0); \
      acc[rt][1] = __builtin_amdgcn_mfma_f32_16x16x32_bf16(af, BUF[1], acc[rt][1], 0,0,0); \
      acc[rt][2] = __builtin_amdgcn_mfma_f32_16x16x32_bf16(af, BUF[2], acc[rt][2], 0,0,0); \
      acc[rt][3] = __builtin_amdgcn_mfma_f32_16x16x32_bf16(af, BUF[3], acc[rt][3], 0,0,0); \
    }                                                                         \
    __builtin_amdgcn_s_setprio(0);                                            \
    {                                                                         \
      _Pragma("unroll")                                                       \
      for (int cc = 0; cc < 4; ++cc)                                          \
        BUF[cc] = *(const bf16x8*)(wbp + cc*512);                             \
      wbp += ((s*4 + (kk) + 2) == 31) ? -(ptrdiff_t)(31*WC_KSTRIDE)           \
                                      : (ptrdiff_t)WC_KSTRIDE;                \
    }                                                                         \
  } while (0)

  #pragma unroll
  for (int s = 0; s < 8; ++s) {
    if (BF16SRC) {
      if (s < 7) { stage_gl(s + 1); __builtin_amdgcn_sched_barrier(0); }
    } else {
      stage_reg(s);
      __syncthreads();
    }
    const char* cb = (const char*)Slds + (s & 1)*16384;
    KSTEP(bA, 0); KSTEP(bB, 1); KSTEP(bA, 2); KSTEP(bB, 3);
    if (BF16SRC) {
      // ops issued after stage(s+1): this phase's 16 B refills -> allow 16
      if (s < 7) PHASE_BARRIER(16);
      // s == 7: the epilogue __syncthreads drains
    } else {
      __syncthreads();
    }
  }
#undef KSTEP

  if (!isV) {
    // K-proj: tanh, dot with Q over 64 k-cols, reduce -> logit per row
    const float* Qb = Q + ((size_t)b*H_ + h)*DK_;
    float q[4];
    #pragma unroll
    for (int cc = 0; cc < 4; ++cc) q[cc] = Qb[16*cc + llo];
    #pragma unroll
    for (int rt = 0; rt < 4; ++rt) {
      #pragma unroll
      for (int r = 0; r < 4; ++r) {
        float pl = q[0]*tanh_fast(acc[rt][0][r]) + q[1]*tanh_fast(acc[rt][1][r])
                 + q[2]*tanh_fast(acc[rt][2][r]) + q[3]*tanh_fast(acc[rt][3][r]);
        pl += __shfl_xor(pl, 1); pl += __shfl_xor(pl, 2);
        pl += __shfl_xor(pl, 4); pl += __shfl_xor(pl, 8);
        if (llo == 0) lpart[hp][rt*16 + lhi*4 + r] = pl;
      }
    }
  } else {
    // V-proj: gelu (erf via A&S 7.1.26) in place
    #pragma unroll
    for (int rt = 0; rt < 4; ++rt)
      #pragma unroll
      for (int cc = 0; cc < 4; ++cc)
        #pragma unroll
        for (int r = 0; r < 4; ++r) {
          float x = acc[rt][cc][r];
          acc[rt][cc][r] = 0.5f*x*(1.f + erf_fast(x*0.70710678118654752f));
        }
  }
  __syncthreads();

  if (isV) {
    // softmax stats over this tile's 64 rows (lane <-> row)
    float lg = lpart[hp][lane] * 0.125f;   // 1/sqrt(64)
    float mx = lg;
    #pragma unroll
    for (int mk = 1; mk < 64; mk <<= 1) mx = fmaxf(mx, __shfl_xor(mx, mk));
    float ev = __expf(lg - mx);
    float sv = ev;
    #pragma unroll
    for (int mk = 1; mk < 64; mk <<= 1) sv += __shfl_xor(sv, mk);

    float er[16];
    #pragma unroll
    for (int rt = 0; rt < 4; ++rt)
      #pragma unroll
      for (int r = 0; r < 4; ++r)
        er[rt*4 + r] = __shfl(ev, rt*16 + lhi*4 + r);

    float* pt = part + (((size_t)b*H_ + h)*NT + t)*PSTRIDE;
    #pragma unroll
    for (int cc = 0; cc < 4; ++cc) {
      float y = 0.f;
      #pragma unroll
      for (int rt = 0; rt < 4; ++rt)
        #pragma unroll
        for (int r = 0; r < 4; ++r)
          y += er[rt*4 + r]*acc[rt][cc][r];
      y += __shfl_xor(y, 16); y += __shfl_xor(y, 32);
      if (lhi == 0) pt[2 + 16*cc + llo] = y;
    }
    if (lane == 0) { pt[0] = mx; pt[1] = sv; }
  }
}

// merge NT tile-partials per (b,h); grid (H, B), block 64
__global__ void finalize_kernel(const float* __restrict__ part,
                                float* __restrict__ out) {
  const int h = blockIdx.x, b = blockIdx.y, v = threadIdx.x;
  const float* p = part + ((size_t)b*H_ + h)*(size_t)NT*PSTRIDE;
  float M = -3.0e38f;
  for (int tt = 0; tt < NT; ++tt) M = fmaxf(M, p[tt*PSTRIDE]);
  float ss = 0.f, y = 0.f;
  for (int tt = 0; tt < NT; ++tt) {
    float w = expf(p[tt*PSTRIDE] - M);
    ss += w*p[tt*PSTRIDE + 1];
    y  += w*p[tt*PSTRIDE + 2 + v];
  }
  out[((size_t)b*H_ + h)*DV_ + v] = y/ss;
}

extern "C" void kernel_launch(void* const* d_in, const int* in_sizes, int n_in,
                              void* d_out, int out_size, void* d_ws, size_t ws_size,
                              hipStream_t stream) {
  const float* X  = (const float*)d_in[0];
  const float* S  = (const float*)d_in[1];
  const float* Wq = (const float*)d_in[2];
  const float* Wk = (const float*)d_in[3];
  const float* Wv = (const float*)d_in[4];
  float* out = (float*)d_out;

  char* ws = (char*)d_ws;
  u16*   Wc    = (u16*)ws;                              // 4 MiB
  float* Qbuf  = (float*)(ws + (4u<<20));               // 128 KiB
  float* part  = (float*)(ws + (4u<<20) + (128u<<10));  // ~4.3 MiB
  u16*   Sb    = (u16*)(ws + (16u<<20));                // 128 MiB (optional)
  const bool useBf = ws_size >= (144ull << 20);

  pack_w_kernel  <<<dim3(H_, 128),  256, 0, stream>>>(Wk, Wv, Wc);
  q_proj_kernel  <<<dim3(H_, B_/4), 256, 0, stream>>>(X, Wq, Qbuf);
  if (useBf) {
    s2bf_kernel       <<<dim3(4096), 256, 0, stream>>>(S, Sb);
    fused_kernel<1>   <<<dim3(8192), 256, 0, stream>>>(S, Sb, Wc, Qbuf, part);
  } else {
    fused_kernel<0>   <<<dim3(8192), 256, 0, stream>>>(S, Sb, Wc, Qbuf, part);
  }
  finalize_kernel<<<dim3(H_, B_),    64, 0, stream>>>(part, out);
}

// Round 21
// 413.778 us; speedup vs baseline: 1.0545x; 1.0074x over previous
//
#include <hip/hip_runtime.h>
#include <math.h>

#define B_   32
#define L_   2048
#define DSEQ 1024
#define DGLB 1024
#define H_   16
#define DK_  64
#define DV_  64
#define LT   64
#define NT   (L_/LT)      // 32
#define PSTRIDE 66        // m, s, y[64]

// Wc2 layout: [h][ks(32)][j(128)][e(32)] bf16; d = ks*32 + e
#define WC_KSTRIDE 4096            // 128*32 elems per k-step
#define WC_HSTRIDE 131072          // 32*4096 elems per head

#define AS1 __attribute__((address_space(1)))
#define AS3 __attribute__((address_space(3)))

using u16    = unsigned short;
using bf16x8 = __attribute__((ext_vector_type(8))) short;
using f32x4  = __attribute__((ext_vector_type(4))) float;

__device__ __forceinline__ u16 f2bf(float x) {
  union { float f; unsigned int u; } v; v.f = x;
  return (u16)((v.u + 0x7fffu + ((v.u >> 16) & 1u)) >> 16);   // RNE
}

__device__ __forceinline__ float tanh_fast(float x) {
  float e = __builtin_exp2f(x * 2.885390081777927f);   // 2*log2(e)
  return 1.f - 2.f/(e + 1.f);
}

__device__ __forceinline__ float erf_fast(float x) {
  float ax = fabsf(x);
  float t  = 1.f/(1.f + 0.3275911f*ax);
  float p  = t*(0.254829592f + t*(-0.284496736f + t*(1.421413741f +
             t*(-1.453152027f + t*1.061405429f))));
  float e  = __builtin_exp2f(-ax*ax*1.4426950408889634f);  // e^{-x^2}
  float r  = 1.f - p*e;
  return copysignf(r, x);
}

#define PHASE_BARRIER(N)                                   \
  do {                                                     \
    __builtin_amdgcn_sched_barrier(0);                     \
    asm volatile("s_waitcnt vmcnt(" #N ")" ::: "memory");  \
    __builtin_amdgcn_s_barrier();                          \
    __builtin_amdgcn_sched_barrier(0);                     \
  } while (0)

// Wc2[h][d>>5][j][d&31]: j<64 -> Wk[h,:,j], else Wv[h,:,j-64]
__global__ void pack_w_kernel(const float* __restrict__ Wk,
                              const float* __restrict__ Wv,
                              u16* __restrict__ Wc) {
  const int h = blockIdx.x, j = blockIdx.y;
  const float* src = (j < DK_) ? (Wk + (size_t)h*DSEQ*DK_ + j)
                               : (Wv + (size_t)h*DSEQ*DV_ + (j - DK_));
  u16* dst = Wc + (size_t)h*WC_HSTRIDE + (size_t)j*32;
  for (int d = threadIdx.x; d < DSEQ; d += blockDim.x)
    dst[(size_t)(d >> 5)*WC_KSTRIDE + (d & 31)] = f2bf(src[(size_t)d*64]);
}

// S (fp32) -> Sb (bf16), flat; 8-elem granules, coalesced
__global__ void s2bf_kernel(const float* __restrict__ S, u16* __restrict__ Sb) {
  const size_t G = (size_t)B_*L_*DSEQ/8;
  for (size_t i = (size_t)blockIdx.x*256 + threadIdx.x; i < G; i += (size_t)4096*256) {
    const float4* sp = (const float4*)(S + i*8);
    float4 v0 = sp[0], v1 = sp[1];
    bf16x8 wv;
    wv[0]=(short)f2bf(v0.x); wv[1]=(short)f2bf(v0.y);
    wv[2]=(short)f2bf(v0.z); wv[3]=(short)f2bf(v0.w);
    wv[4]=(short)f2bf(v1.x); wv[5]=(short)f2bf(v1.y);
    wv[6]=(short)f2bf(v1.z); wv[7]=(short)f2bf(v1.w);
    *(bf16x8*)(Sb + i*8) = wv;
  }
}

// Q[b][h][k] = tanh(sum_d X[b,d]*Wq[h,d,k]); grid (H, B/4), 256 thr.
// Coalesced (r17): threads (dd=tid>>6, k=tid&63); LDS reduce over dd.
__global__ void q_proj_kernel(const float* __restrict__ X,
                              const float* __restrict__ Wq,
                              float* __restrict__ Q) {
  __shared__ float red[4][4][64];   // [dd][bb][k]
  const int h = blockIdx.x, b0 = blockIdx.y*4;
  const int k = threadIdx.x & 63, dd = threadIdx.x >> 6;
  const float* w = Wq + (size_t)h*DGLB*DK_ + (size_t)dd*256*DK_ + k;
  float a0=0.f, a1=0.f, a2=0.f, a3=0.f;
  for (int d = 0; d < 256; ++d) {
    float wv = w[(size_t)d*DK_];
    a0 += X[(size_t)(b0+0)*DGLB + dd*256 + d]*wv;
    a1 += X[(size_t)(b0+1)*DGLB + dd*256 + d]*wv;
    a2 += X[(size_t)(b0+2)*DGLB + dd*256 + d]*wv;
    a3 += X[(size_t)(b0+3)*DGLB + dd*256 + d]*wv;
  }
  red[dd][0][k]=a0; red[dd][1][k]=a1; red[dd][2][k]=a2; red[dd][3][k]=a3;
  __syncthreads();
  if (dd == 0) {
    #pragma unroll
    for (int bb = 0; bb < 4; ++bb) {
      float s = red[0][bb][k]+red[1][bb][k]+red[2][bb][k]+red[3][bb][k];
      Q[((size_t)(b0+bb)*H_+h)*DK_+k] = tanhf(s);
    }
  }
}

// grid: 4096 blocks, 256 thr = 4 waves, 2 blocks/CU (launch_bounds(256,2)
// -> 256-reg budget; live ~= acc 128 + B 64 + misc 25 = 217, spill-free).
// HIGH-INTENSITY WAVE: wave w = ONE head (g*4+w), 64 rows x 128 cols
// (K 64 + V 64 fused), acc[4][8]. Per KSTEP: 32 MFMA per 4 ds_read
// (2x MFMA per A-byte and per issue slot vs r20 — attacks the measured
// dependency-stall bound: r20 had NO saturated pipe, all <=40%).
// Epilogue fully wave-local (logits + softmax + gelu + weighted sum).
// Mapping: xcd=id&7; g=xcd>>1 (head-group, Wc slice 1 MB L2-safe);
// cpar=xcd&1; mm=id>>3; tile=((mm+g*128)&511)*2|cpar. 4 readers/tile,
// de-phased by g*128 -> sequential, L3-served (r18 mechanism).
// Pipeline (r20 2-buffer): phase s computes buf[s&1], stage(s+1) issued
// at phase start; end-of-phase counted vmcnt(32) (= this phase's 32 B
// refills; forces stage(s+1) complete, keeps B prefetch in flight).
template<int BF16SRC>
__global__ __launch_bounds__(256, 2) void fused_kernel(
    const float* __restrict__ S, const u16* __restrict__ Sb,
    const u16* __restrict__ Wc, const float* __restrict__ Q,
    float* __restrict__ part) {
  __shared__ u16   Slds[2*64*128];   // 2 x 16 KB, rows 256 B
  __shared__ float lpart[4][64];     // per-wave logit staging

  const int id   = blockIdx.x;
  const int xcd  = id & 7;
  const int g    = xcd >> 1;         // head-group 0..3 (heads 4g..4g+3)
  const int cpar = xcd & 1;          // tile parity
  const int mm   = id >> 3;          // 0..511
  const int tile = (((mm + (g << 7)) & 511) << 1) | cpar;   // 0..1023
  const int t    = tile & (NT-1), b = tile >> 5;

  const int tid  = threadIdx.x;
  const int wave = tid >> 6, lane = tid & 63;
  const int lhi  = lane >> 4, llo = lane & 15;
  const int h    = g*4 + wave;       // one head per wave

  // B cols j = c*16 + llo, c 0..7 (c<4 = K cols, c>=4 = V cols)
  const u16* wb = Wc + (size_t)h*WC_HSTRIDE + (size_t)llo*32 + lhi*8;
  int arow[4];
  #pragma unroll
  for (int rt = 0; rt < 4; ++rt) arow[rt] = (rt*16 + llo)*256;  // bytes

  const u16*   Sv = Sb + ((size_t)b*L_ + (size_t)t*LT)*DSEQ;
  const float* Sf = S  + ((size_t)b*L_ + (size_t)t*LT)*DSEQ;

  // stage sub-tile (sub: 64 rows x 128 k = 16 KB) into buf[sub&1]
  auto stage_gl = [&](int sub) {
    const int bs = (sub & 1) * 8192;           // u16 offset (16 KB)
    const int ko = (sub & 7) * 128;
    #pragma unroll
    for (int it = 0; it < 4; ++it) {
      const int jj  = wave*4 + it;
      const int row = 4*jj + (lane >> 4);
      const int gg  = (lane & 15) ^ (row & 15);
      const u16* gp = Sv + (size_t)row*DSEQ + ko + (gg << 3);
      __builtin_amdgcn_global_load_lds(
          (const AS1 void*)gp, (AS3 void*)(Slds + bs + jj*512), 16, 0, 0);
    }
  };
  auto stage_reg = [&](int sub) {              // fp32 fallback
    const int bs = (sub & 1) * 16384;          // bytes
    const int ko = (sub & 7) * 128;
    #pragma unroll
    for (int it = 0; it < 4; ++it) {
      int f = it*256 + tid, row = f >> 4, q = f & 15;
      int gg = q ^ (row & 15);
      const float4* sp = (const float4*)(Sf + (size_t)row*DSEQ + ko + gg*8);
      float4 v0 = sp[0], v1 = sp[1];
      bf16x8 wv;
      wv[0]=(short)f2bf(v0.x); wv[1]=(short)f2bf(v0.y);
      wv[2]=(short)f2bf(v0.z); wv[3]=(short)f2bf(v0.w);
      wv[4]=(short)f2bf(v1.x); wv[5]=(short)f2bf(v1.y);
      wv[6]=(short)f2bf(v1.z); wv[7]=(short)f2bf(v1.w);
      *(bf16x8*)((char*)Slds + bs + row*256 + q*16) = wv;
    }
  };

  f32x4 acc[4][8];
  #pragma unroll
  for (int rt = 0; rt < 4; ++rt)
    #pragma unroll
    for (int cc = 0; cc < 8; ++cc) acc[rt][cc] = {0.f,0.f,0.f,0.f};

  // prologue: stage sub 0 (pinned first), then B init (steps 0,1)
  if (BF16SRC) {
    stage_gl(0);
    __builtin_amdgcn_sched_barrier(0);
  }
  bf16x8 bA[8], bB[8];
  #pragma unroll
  for (int cc = 0; cc < 8; ++cc) bA[cc] = *(const bf16x8*)(wb + (size_t)0*WC_KSTRIDE + cc*512);
  #pragma unroll
  for (int cc = 0; cc < 8; ++cc) bB[cc] = *(const bf16x8*)(wb + (size_t)1*WC_KSTRIDE + cc*512);
  const u16* wbp = wb + (size_t)2*WC_KSTRIDE;  // rolling refill pointer
  if (BF16SRC) PHASE_BARRIER(16);              // stage(0) done; B-init in flight

  // one k-step (32 elems): 4 ds_read + 32 MFMA; refill BUF with step +2
#define KSTEP(BUF, kk)                                                        \
  do {                                                                        \
    const int colb = (((kk)*4 + lhi) ^ llo) << 4;                             \
    __builtin_amdgcn_s_setprio(1);                                            \
    _Pragma("unroll")                                                         \
    for (int rt = 0; rt < 4; ++rt) {                                          \
      bf16x8 af = *(const bf16x8*)(cb + arow[rt] + colb);                     \
      _Pragma("unroll")                                                       \
      for (int cc = 0; cc < 8; ++cc)                                          \
        acc[rt][cc] = __builtin_amdgcn_mfma_f32_16x16x32_bf16(af, BUF[cc], acc[rt][cc], 0,0,0); \
    }                                                                         \
    __builtin_amdgcn_s_setprio(0);                                            \
    {                                                                         \
      _Pragma("unroll")                                                       \
      for (int cc = 0; cc < 8; ++cc)                                          \
        BUF[cc] = *(const bf16x8*)(wbp + cc*512);                             \
      wbp += ((s*4 + (kk) + 2) == 31) ? -(ptrdiff_t)(31*WC_KSTRIDE)           \
                                      : (ptrdiff_t)WC_KSTRIDE;                \
    }                                                                         \
  } while (0)

  #pragma unroll
  for (int s = 0; s < 8; ++s) {
    if (BF16SRC) {
      if (s < 7) { stage_gl(s + 1); __builtin_amdgcn_sched_barrier(0); }
    } else {
      stage_reg(s);
      __syncthreads();
    }
    const char* cb = (const char*)Slds + (s & 1)*16384;
    KSTEP(bA, 0); KSTEP(bB, 1); KSTEP(bA, 2); KSTEP(bB, 3);
    if (BF16SRC) {
      // ops issued after stage(s+1): this phase's 32 B refills -> allow 32
      if (s < 7) PHASE_BARRIER(32);
      // s == 7: the epilogue __syncthreads drains
    } else {
      __syncthreads();
    }
  }
#undef KSTEP

  // ---- epilogue, fully wave-local (wave = head h) ----
  // logits: K cols are acc[.][0..3]
  {
    const float* Qb = Q + ((size_t)b*H_ + h)*DK_;
    float q[4];
    #pragma unroll
    for (int cc = 0; cc < 4; ++cc) q[cc] = Qb[16*cc + llo];
    #pragma unroll
    for (int rt = 0; rt < 4; ++rt) {
      #pragma unroll
      for (int r = 0; r < 4; ++r) {
        float pl = q[0]*tanh_fast(acc[rt][0][r]) + q[1]*tanh_fast(acc[rt][1][r])
                 + q[2]*tanh_fast(acc[rt][2][r]) + q[3]*tanh_fast(acc[rt][3][r]);
        pl += __shfl_xor(pl, 1); pl += __shfl_xor(pl, 2);
        pl += __shfl_xor(pl, 4); pl += __shfl_xor(pl, 8);
        if (llo == 0) lpart[wave][rt*16 + lhi*4 + r] = pl;
      }
    }
  }
  // gelu on V cols acc[.][4..7]
  #pragma unroll
  for (int rt = 0; rt < 4; ++rt)
    #pragma unroll
    for (int cc = 4; cc < 8; ++cc)
      #pragma unroll
      for (int r = 0; r < 4; ++r) {
        float x = acc[rt][cc][r];
        acc[rt][cc][r] = 0.5f*x*(1.f + erf_fast(x*0.70710678118654752f));
      }
  __syncthreads();   // lpart visibility (and drains final staging)

  {
    // softmax stats over this tile's 64 rows (lane <-> row)
    float lg = lpart[wave][lane] * 0.125f;   // 1/sqrt(64)
    float mx = lg;
    #pragma unroll
    for (int mk = 1; mk < 64; mk <<= 1) mx = fmaxf(mx, __shfl_xor(mx, mk));
    float ev = __expf(lg - mx);
    float sv = ev;
    #pragma unroll
    for (int mk = 1; mk < 64; mk <<= 1) sv += __shfl_xor(sv, mk);

    float er[16];
    #pragma unroll
    for (int rt = 0; rt < 4; ++rt)
      #pragma unroll
      for (int r = 0; r < 4; ++r)
        er[rt*4 + r] = __shfl(ev, rt*16 + lhi*4 + r);

    float* pt = part + (((size_t)b*H_ + h)*NT + t)*PSTRIDE;
    #pragma unroll
    for (int cc = 0; cc < 4; ++cc) {
      float y = 0.f;
      #pragma unroll
      for (int rt = 0; rt < 4; ++rt)
        #pragma unroll
        for (int r = 0; r < 4; ++r)
          y += er[rt*4 + r]*acc[rt][cc + 4][r];
      y += __shfl_xor(y, 16); y += __shfl_xor(y, 32);
      if (lhi == 0) pt[2 + 16*cc + llo] = y;
    }
    if (lane == 0) { pt[0] = mx; pt[1] = sv; }
  }
}

// merge NT tile-partials per (b,h); grid (H, B), block 64
__global__ void finalize_kernel(const float* __restrict__ part,
                                float* __restrict__ out) {
  const int h = blockIdx.x, b = blockIdx.y, v = threadIdx.x;
  const float* p = part + ((size_t)b*H_ + h)*(size_t)NT*PSTRIDE;
  float M = -3.0e38f;
  for (int tt = 0; tt < NT; ++tt) M = fmaxf(M, p[tt*PSTRIDE]);
  float ss = 0.f, y = 0.f;
  for (int tt = 0; tt < NT; ++tt) {
    float w = expf(p[tt*PSTRIDE] - M);
    ss += w*p[tt*PSTRIDE + 1];
    y  += w*p[tt*PSTRIDE + 2 + v];
  }
  out[((size_t)b*H_ + h)*DV_ + v] = y/ss;
}

extern "C" void kernel_launch(void* const* d_in, const int* in_sizes, int n_in,
                              void* d_out, int out_size, void* d_ws, size_t ws_size,
                              hipStream_t stream) {
  const float* X  = (const float*)d_in[0];
  const float* S  = (const float*)d_in[1];
  const float* Wq = (const float*)d_in[2];
  const float* Wk = (const float*)d_in[3];
  const float* Wv = (const float*)d_in[4];
  float* out = (float*)d_out;

  char* ws = (char*)d_ws;
  u16*   Wc    = (u16*)ws;                              // 4 MiB
  float* Qbuf  = (float*)(ws + (4u<<20));               // 128 KiB
  float* part  = (float*)(ws + (4u<<20) + (128u<<10));  // ~4.3 MiB
  u16*   Sb    = (u16*)(ws + (16u<<20));                // 128 MiB (optional)
  const bool useBf = ws_size >= (144ull << 20);

  pack_w_kernel  <<<dim3(H_, 128),  256, 0, stream>>>(Wk, Wv, Wc);
  q_proj_kernel  <<<dim3(H_, B_/4), 256, 0, stream>>>(X, Wq, Qbuf);
  if (useBf) {
    s2bf_kernel       <<<dim3(4096), 256, 0, stream>>>(S, Sb);
    fused_kernel<1>   <<<dim3(4096), 256, 0, stream>>>(S, Sb, Wc, Qbuf, part);
  } else {
    fused_kernel<0>   <<<dim3(4096), 256, 0, stream>>>(S, Sb, Wc, Qbuf, part);
  }
  finalize_kernel<<<dim3(H_, B_),    64, 0, stream>>>(part, out);
}